// Round 8
// baseline (249.343 us; speedup 1.0000x reference)
//
#include <hip/hip_runtime.h>
#include <hip/hip_bf16.h>

typedef short short8 __attribute__((ext_vector_type(8)));
typedef float f32x4 __attribute__((ext_vector_type(4)));

__device__ __forceinline__ ushort f2bf(float f) {
    union { float f; unsigned u; } v; v.f = f;
    unsigned r = v.u + 0x7fff + ((v.u >> 16) & 1);
    return (ushort)(r >> 16);
}

__device__ __forceinline__ void gload_lds16(const void* g, void* l) {
    __builtin_amdgcn_global_load_lds((const __attribute__((address_space(1))) void*)g,
                                     (__attribute__((address_space(3))) void*)l, 16, 0, 0);
}

// ---------------- merged prep kernel ----------------
// roles by blockIdx: [0,2048) conv nf->bf16 | [2048,2560) index | [2560,2816) pack W2
// [2816,3329) wc: Wc=[We@W1a;We@W1b] written DIRECTLY in packed pk1 layout; +bc block.

__global__ __launch_bounds__(256) void prep_k(
    const float* __restrict__ node_feat, ushort* __restrict__ nf_bf, int n4,
    const int* __restrict__ ec, const int* __restrict__ nnodes, const int* __restrict__ ncand,
    int G, int E, int* __restrict__ idxb, float* __restrict__ out_idx,
    const float* __restrict__ W2, ushort* __restrict__ pk2,
    const float* __restrict__ We, const float* __restrict__ be,
    const float* __restrict__ W1, const float* __restrict__ b1,
    ushort* __restrict__ pk1, float* __restrict__ bc)
{
    const int b = blockIdx.x;
    if (b < 2048) {
        // ---- conv fp32 -> bf16 ----
        int i = b * 256 + threadIdx.x;
        const int stride = 2048 * 256;
        for (int j = i; j < n4; j += stride) {
            float4 v = ((const float4*)node_feat)[j];
            ushort4 o;
            o.x = f2bf(v.x); o.y = f2bf(v.y); o.z = f2bf(v.z); o.w = f2bf(v.w);
            ((ushort4*)nf_bf)[j] = o;
        }
    } else if (b < 2560) {
        // ---- index build ----
        __shared__ int snoff[257];
        __shared__ int seoff[257];
        if (threadIdx.x == 0) {
            int a = 0, c = 0;
            for (int g = 0; g < G; g++) {
                snoff[g] = a; a += nnodes[g];
                c += ncand[g]; seoff[g] = c;
            }
        }
        __syncthreads();
        int e = (b - 2048) * 256 + threadIdx.x;
        if (e >= E) return;
        int lo = 0, hi = G - 1;
        while (lo < hi) {
            int mid = (lo + hi) >> 1;
            if (seoff[mid] > e) hi = mid; else lo = mid + 1;
        }
        int off = snoff[lo];
        int g0 = ec[2 * e] + off, g1 = ec[2 * e + 1] + off;
        idxb[2 * e] = g0; idxb[2 * e + 1] = g1;
        out_idx[2 * e] = (float)g0; out_idx[2 * e + 1] = (float)g1;
    } else if (b < 2816) {
        // ---- pack W2 [256][256] -> pk2 (K=256, K/32=8) ----
        int id = (b - 2560) * 256 + threadIdx.x;
        int j = id & 7;
        int l = (id >> 3) & 63;
        int S = (id >> 9) & 7;
        int F = id >> 12;
        int n = F * 16 + (l & 15);
        int k = S * 32 + (l >> 4) * 8 + j;
        pk2[id] = f2bf(W2[(size_t)k * 256 + n]);
    } else {
        // ---- wc: row k of Wc computed and written packed into pk1 (K=512) ----
        int k = b - 2816;          // 0..512
        int n = threadIdx.x;
        if (k < 512) {
            const float* werow = We + (size_t)(k & 255) * 256;
            const float* w1col = W1 + ((k >> 8) ? 256 * 256 : 0);
            float acc = 0.f;
#pragma unroll 4
            for (int d = 0; d < 256; d++)
                acc += werow[d] * w1col[(size_t)d * 256 + n];
            int j = k & 7;
            int S = k >> 5;
            int F = n >> 4;
            int l = ((k >> 3) & 3) * 16 + (n & 15);
            pk1[((size_t)(F * 16 + S) * 64 + l) * 8 + j] = f2bf(acc);
        } else {
            float acc = b1[n];
#pragma unroll 4
            for (int d = 0; d < 256; d++)
                acc += be[d] * (W1[(size_t)d * 256 + n] + W1[(size_t)(d + 256) * 256 + n]);
            bc[n] = acc;
        }
    }
}

// ---------------- fused MLP: scores = relu(relu(gath(nf)@Wc+bc)@W2+b2)@W3+b3 ----------------
// BM=128 edges/block, 1024 threads = 16 waves as 4 wm x 4 wn, per-wave 32x64 output.
// (4x4 grid: A-fragment LDS re-read factor = 4 instead of 8 -> DS pipe halved.)
// Phase 1: K=512 gather-GEMM, 3-deep LDS ring (swizzled via pre-swizzled global src),
//          B-fragments (packed) in registers, counted vmcnt at tile boundaries.
// h1 -> LDS (aliases ring). Phase 2: K=256 from LDS, barrier-free. Fused W3 epilogue.

#define LOADB(bk, Bp, KDIV32, t)                                                            \
    _Pragma("unroll") for (int nf = 0; nf < 4; nf++)                                        \
    _Pragma("unroll") for (int kk = 0; kk < 2; kk++)                                        \
        bk[nf * 2 + kk] = *(const short8*)&Bp[((size_t)((wn * 4 + nf) * (KDIV32)            \
                                               + (t) * 2 + kk) * 64 + l) * 8];

#define COMPUTE1(bi, bk)                                                                    \
    {                                                                                       \
        short8 af[4];                                                                       \
        _Pragma("unroll") for (int mf = 0; mf < 2; mf++)                                    \
        _Pragma("unroll") for (int kk = 0; kk < 2; kk++)                                    \
            af[mf * 2 + kk] = *(const short8*)&ring[(bi) * 8192 +                           \
                (wm * 32 + mf * 16 + llo) * 64 + (((kk * 4 + lhi) ^ (llo & 7)) * 8)];       \
        __builtin_amdgcn_s_setprio(1);                                                      \
        _Pragma("unroll") for (int mf = 0; mf < 2; mf++)                                    \
        _Pragma("unroll") for (int nf = 0; nf < 4; nf++)                                    \
        _Pragma("unroll") for (int kk = 0; kk < 2; kk++)                                    \
            acc[mf][nf] = __builtin_amdgcn_mfma_f32_16x16x32_bf16(                          \
                bk[nf * 2 + kk], af[mf * 2 + kk], acc[mf][nf], 0, 0, 0);                    \
        __builtin_amdgcn_s_setprio(0);                                                      \
    }

#define COMPUTE2(t2, bk)                                                                    \
    {                                                                                       \
        short8 af[4];                                                                       \
        _Pragma("unroll") for (int mf = 0; mf < 2; mf++)                                    \
        _Pragma("unroll") for (int kk = 0; kk < 2; kk++)                                    \
            af[mf * 2 + kk] = *(const short8*)&h1lds[                                       \
                (wm * 32 + mf * 16 + llo) * 256 +                                           \
                (((t2) * 8 | ((kk * 4 + lhi) ^ (llo & 7))) * 8)];                           \
        __builtin_amdgcn_s_setprio(1);                                                      \
        _Pragma("unroll") for (int mf = 0; mf < 2; mf++)                                    \
        _Pragma("unroll") for (int nf = 0; nf < 4; nf++)                                    \
        _Pragma("unroll") for (int kk = 0; kk < 2; kk++)                                    \
            acc[mf][nf] = __builtin_amdgcn_mfma_f32_16x16x32_bf16(                          \
                bk[nf * 2 + kk], af[mf * 2 + kk], acc[mf][nf], 0, 0, 0);                    \
        __builtin_amdgcn_s_setprio(0);                                                      \
    }

#define TILE_BARRIER(n)                                                                     \
    __builtin_amdgcn_sched_barrier(0);                                                      \
    asm volatile("s_waitcnt vmcnt(" #n ")" ::: "memory");                                   \
    __builtin_amdgcn_s_barrier();                                                           \
    __builtin_amdgcn_sched_barrier(0);

__global__ __launch_bounds__(1024, 4) void fused_mlp(
    const ushort* __restrict__ nf_bf, const int* __restrict__ idx,
    const ushort* __restrict__ pk1, const float* __restrict__ bc,
    const ushort* __restrict__ pk2, const float* __restrict__ b2,
    const float* __restrict__ W3, const float* __restrict__ b3,
    float* __restrict__ scores)
{
    __shared__ __align__(16) ushort smem[34816];   // 68 KB: ring 3x16K, h1 aliases [0,64K), sc at +64K
    ushort* ring = smem;
    ushort* h1lds = smem;
    float* sc = (float*)&smem[32768];              // [4][128][2] = 4 KB

    const int tid = threadIdx.x;
    const int w = tid >> 6, l = tid & 63;
    const int llo = l & 15, lhi = l >> 4;
    const int wm = w >> 2, wn = w & 3;
    const int work = ((blockIdx.x & 7) << 7) + (blockIdx.x >> 3);   // chunked XCD swizzle
    const int m0 = work * 128;

    // staging: each thread loads one row-slice; row = tid>>3, swizzled col chunk
    const int srow = tid >> 3;
    const int swz = 8 * ((l & 7) ^ ((l >> 3) & 7));
    const int2 ip = *(const int2*)&idx[2 * (m0 + srow)];
    const ushort* rp0 = nf_bf + (size_t)ip.x * 256 + swz;
    const ushort* rp1 = nf_bf + (size_t)ip.y * 256 + swz;

    f32x4 acc[2][4];
#pragma unroll
    for (int mf = 0; mf < 2; mf++)
#pragma unroll
        for (int nf = 0; nf < 4; nf++) acc[mf][nf] = {0.f, 0.f, 0.f, 0.f};

    short8 bkA[8], bkB[8];

    auto stageA = [&](int bi, int t) {
        const ushort* src = ((t < 4) ? rp0 : rp1) + ((t & 3) * 64);
        gload_lds16(src, &ring[bi * 8192 + w * 512]);
    };

    // ---- prologue: stage tiles 0,1 ----
    stageA(0, 0);            // 1
    LOADB(bkA, pk1, 16, 0)   // +8 = 9
    stageA(1, 1);            // +1 = 10
    TILE_BARRIER(9)          // stage(0) retired

    // ---- phase 1: 8 K-tiles, 3-deep ring ----
#pragma unroll
    for (int t = 0; t < 8; t++) {
        if (t + 1 < 8) {
            if (t & 1) { LOADB(bkA, pk1, 16, t + 1) } else { LOADB(bkB, pk1, 16, t + 1) }
        }
        if (t + 2 < 8) stageA((t + 2) % 3, t + 2);
        if (t & 1) COMPUTE1(t % 3, bkB)
        else       COMPUTE1(t % 3, bkA)
        if (t < 6)      { TILE_BARRIER(9) }
        else if (t == 6){ TILE_BARRIER(8) }
    }

    // prefetch phase-2 B tile 0 while epilogue runs
    LOADB(bkA, pk2, 8, 0)
    __syncthreads();   // all ring reads done; safe to overwrite with h1

    // ---- epilogue 1: h1 = relu(acc + bc) -> LDS (bf16, XOR-swizzled chunks) ----
    {
#pragma unroll
        for (int nf = 0; nf < 4; nf++) {
            int colb = wn * 64 + nf * 16 + lhi * 4;
            float4 bv = *(const float4*)&bc[colb];
            int c = colb >> 3;
            int coff = colb & 7;
#pragma unroll
            for (int mf = 0; mf < 2; mf++) {
                int row = wm * 32 + mf * 16 + llo;
                float v0 = fmaxf(acc[mf][nf][0] + bv.x, 0.f);
                float v1 = fmaxf(acc[mf][nf][1] + bv.y, 0.f);
                float v2 = fmaxf(acc[mf][nf][2] + bv.z, 0.f);
                float v3 = fmaxf(acc[mf][nf][3] + bv.w, 0.f);
                ushort4 o;
                o.x = f2bf(v0); o.y = f2bf(v1); o.z = f2bf(v2); o.w = f2bf(v3);
                int cs = (c & 24) | ((c & 7) ^ (row & 7));
                *(ushort4*)&h1lds[row * 256 + cs * 8 + coff] = o;
            }
        }
    }
    __syncthreads();   // h1 visible

#pragma unroll
    for (int mf = 0; mf < 2; mf++)
#pragma unroll
        for (int nf = 0; nf < 4; nf++) acc[mf][nf] = {0.f, 0.f, 0.f, 0.f};

    // ---- phase 2: 4 K-tiles from LDS, barrier-free ----
#pragma unroll
    for (int t2 = 0; t2 < 4; t2++) {
        if (t2 + 1 < 4) {
            if (t2 & 1) { LOADB(bkA, pk2, 8, t2 + 1) } else { LOADB(bkB, pk2, 8, t2 + 1) }
        }
        if (t2 & 1) COMPUTE2(t2, bkB)
        else        COMPUTE2(t2, bkA)
    }

    // ---- epilogue 2: scores = relu(acc + b2) @ W3 + b3 ----
    float p0[2], p1[2];
#pragma unroll
    for (int mf = 0; mf < 2; mf++) { p0[mf] = 0.f; p1[mf] = 0.f; }
#pragma unroll
    for (int nf = 0; nf < 4; nf++) {
        int colb = wn * 64 + nf * 16 + lhi * 4;
        float4 b2v = *(const float4*)&b2[colb];
        float2 w3a = ((const float2*)W3)[colb + 0];
        float2 w3b = ((const float2*)W3)[colb + 1];
        float2 w3c = ((const float2*)W3)[colb + 2];
        float2 w3d = ((const float2*)W3)[colb + 3];
#pragma unroll
        for (int mf = 0; mf < 2; mf++) {
            float v0 = fmaxf(acc[mf][nf][0] + b2v.x, 0.f);
            float v1 = fmaxf(acc[mf][nf][1] + b2v.y, 0.f);
            float v2 = fmaxf(acc[mf][nf][2] + b2v.z, 0.f);
            float v3 = fmaxf(acc[mf][nf][3] + b2v.w, 0.f);
            p0[mf] += v0 * w3a.x + v1 * w3b.x + v2 * w3c.x + v3 * w3d.x;
            p1[mf] += v0 * w3a.y + v1 * w3b.y + v2 * w3c.y + v3 * w3d.y;
        }
    }
#pragma unroll
    for (int mf = 0; mf < 2; mf++) {
        p0[mf] += __shfl_xor(p0[mf], 16); p0[mf] += __shfl_xor(p0[mf], 32);
        p1[mf] += __shfl_xor(p1[mf], 16); p1[mf] += __shfl_xor(p1[mf], 32);
    }
    if (l < 16) {
#pragma unroll
        for (int mf = 0; mf < 2; mf++) {
            int r = wm * 32 + mf * 16 + l;
            sc[(wn * 128 + r) * 2 + 0] = p0[mf];
            sc[(wn * 128 + r) * 2 + 1] = p1[mf];
        }
    }
    __syncthreads();
    if (tid < 256) {
        int row = tid >> 1, j = tid & 1;
        float s = b3[j];
#pragma unroll
        for (int q = 0; q < 4; q++) s += sc[(q * 128 + row) * 2 + j];
        scores[(size_t)(m0 + row) * 2 + j] = s;
    }
}

// ---------------- launch ----------------

extern "C" void kernel_launch(void* const* d_in, const int* in_sizes, int n_in,
                              void* d_out, int out_size, void* d_ws, size_t ws_size,
                              hipStream_t stream) {
    const float* node_feat = (const float*)d_in[0];
    const int* edge_candidate = (const int*)d_in[1];
    const int* nnodes = (const int*)d_in[2];
    const int* ncand = (const int*)d_in[3];
    const float* W_enc = (const float*)d_in[4];
    const float* b_enc = (const float*)d_in[5];
    const float* W1 = (const float*)d_in[6];
    const float* b1 = (const float*)d_in[7];
    const float* W2 = (const float*)d_in[8];
    const float* b2 = (const float*)d_in[9];
    const float* W3 = (const float*)d_in[10];
    const float* b3 = (const float*)d_in[11];

    const int D = 256;
    const int G = in_sizes[2];            // 64
    const int TOTN = in_sizes[0] / D;     // 32768
    const int E = in_sizes[1] / 2;        // 131072
    const int ENS = in_sizes[11];         // 2

    char* wsb = (char*)d_ws;
    size_t off = 0;
    auto alloc = [&](size_t bytes) -> void* {
        void* p = wsb + off;
        off += (bytes + 255) & ~(size_t)255;
        return p;
    };
    ushort* nf_bf = (ushort*)alloc((size_t)TOTN * D * 2);
    ushort* pk1   = (ushort*)alloc((size_t)512 * 256 * 2);
    ushort* pk2   = (ushort*)alloc((size_t)256 * 256 * 2);
    float*  bc    = (float*)alloc(256 * 4);
    int* idxb     = (int*)alloc((size_t)E * 2 * 4);

    float* scores_out = (float*)d_out;
    float* idx_out = scores_out + (size_t)E * ENS;

    // merged prep: conv | index | pack W2 | wc->pk1 + bc
    prep_k<<<3329, 256, 0, stream>>>(
        node_feat, nf_bf, TOTN * D / 4,
        edge_candidate, nnodes, ncand, G, E, idxb, idx_out,
        W2, pk2,
        W_enc, b_enc, W1, b1, pk1, bc);

    // fused L1+L2+L3
    fused_mlp<<<E / 128, 1024, 0, stream>>>(nf_bf, idxb, pk1, bc, pk2, b2, W3, b3, scores_out);
}

// Round 9
// 77.344 us; speedup vs baseline: 3.2238x; 3.2238x over previous
//
#include <hip/hip_runtime.h>
#include <hip/hip_bf16.h>

typedef short short8 __attribute__((ext_vector_type(8)));
typedef float f32x4 __attribute__((ext_vector_type(4)));

__device__ __forceinline__ ushort f2bf(float f) {
    union { float f; unsigned u; } v; v.f = f;
    unsigned r = v.u + 0x7fff + ((v.u >> 16) & 1);
    return (ushort)(r >> 16);
}

__device__ __forceinline__ void gload_lds16(const void* g, void* l) {
    __builtin_amdgcn_global_load_lds((const __attribute__((address_space(1))) void*)g,
                                     (__attribute__((address_space(3))) void*)l, 16, 0, 0);
}

// ---------------- merged prep kernel ----------------
// roles by blockIdx: [0,2048) conv nf->bf16 | [2048,2560) index | [2560,2816) pack W2
// [2816,3329) wc: Wc=[We@W1a;We@W1b] written DIRECTLY in packed pk1 layout; +bc block.

__global__ __launch_bounds__(256) void prep_k(
    const float* __restrict__ node_feat, ushort* __restrict__ nf_bf, int n4,
    const int* __restrict__ ec, const int* __restrict__ nnodes, const int* __restrict__ ncand,
    int G, int E, int* __restrict__ idxb, float* __restrict__ out_idx,
    const float* __restrict__ W2, ushort* __restrict__ pk2,
    const float* __restrict__ We, const float* __restrict__ be,
    const float* __restrict__ W1, const float* __restrict__ b1,
    ushort* __restrict__ pk1, float* __restrict__ bc)
{
    const int b = blockIdx.x;
    if (b < 2048) {
        int i = b * 256 + threadIdx.x;
        const int stride = 2048 * 256;
        for (int j = i; j < n4; j += stride) {
            float4 v = ((const float4*)node_feat)[j];
            ushort4 o;
            o.x = f2bf(v.x); o.y = f2bf(v.y); o.z = f2bf(v.z); o.w = f2bf(v.w);
            ((ushort4*)nf_bf)[j] = o;
        }
    } else if (b < 2560) {
        __shared__ int snoff[257];
        __shared__ int seoff[257];
        if (threadIdx.x == 0) {
            int a = 0, c = 0;
            for (int g = 0; g < G; g++) {
                snoff[g] = a; a += nnodes[g];
                c += ncand[g]; seoff[g] = c;
            }
        }
        __syncthreads();
        int e = (b - 2048) * 256 + threadIdx.x;
        if (e >= E) return;
        int lo = 0, hi = G - 1;
        while (lo < hi) {
            int mid = (lo + hi) >> 1;
            if (seoff[mid] > e) hi = mid; else lo = mid + 1;
        }
        int off = snoff[lo];
        int g0 = ec[2 * e] + off, g1 = ec[2 * e + 1] + off;
        idxb[2 * e] = g0; idxb[2 * e + 1] = g1;
        out_idx[2 * e] = (float)g0; out_idx[2 * e + 1] = (float)g1;
    } else if (b < 2816) {
        int id = (b - 2560) * 256 + threadIdx.x;
        int j = id & 7;
        int l = (id >> 3) & 63;
        int S = (id >> 9) & 7;
        int F = id >> 12;
        int n = F * 16 + (l & 15);
        int k = S * 32 + (l >> 4) * 8 + j;
        pk2[id] = f2bf(W2[(size_t)k * 256 + n]);
    } else {
        int k = b - 2816;          // 0..512
        int n = threadIdx.x;
        if (k < 512) {
            const float* werow = We + (size_t)(k & 255) * 256;
            const float* w1col = W1 + ((k >> 8) ? 256 * 256 : 0);
            float acc = 0.f;
#pragma unroll 4
            for (int d = 0; d < 256; d++)
                acc += werow[d] * w1col[(size_t)d * 256 + n];
            int j = k & 7;
            int S = k >> 5;
            int F = n >> 4;
            int l = ((k >> 3) & 3) * 16 + (n & 15);
            pk1[((size_t)(F * 16 + S) * 64 + l) * 8 + j] = f2bf(acc);
        } else {
            float acc = b1[n];
#pragma unroll 4
            for (int d = 0; d < 256; d++)
                acc += be[d] * (W1[(size_t)d * 256 + n] + W1[(size_t)(d + 256) * 256 + n]);
            bc[n] = acc;
        }
    }
}

// ---------------- fused MLP: scores = relu(relu(gath(nf)@Wc+bc)@W2+b2)@W3+b3 ----------------
// BM=256 edges/block, 512 threads = 8 waves (2 wm x 4 wn), wave = 128x64 output (HK geometry).
// VGPR budget (cap 256): acc 128 + B-dbuf 64 + af 16 (mf in groups of 2) + ptrs ~16 = ~240.
// Phase 1: K=512 gather-GEMM, 3x32KB LDS ring, B in regs, counted vmcnt at boundaries.
// h1(256x256 bf16, 128KB) -> LDS aliasing ring. Phase 2: K=256 from LDS, barrier-free.

#define LOADB(bk, Bp, KDIV32, t)                                                            \
    _Pragma("unroll") for (int nf = 0; nf < 4; nf++)                                        \
    _Pragma("unroll") for (int kk = 0; kk < 2; kk++)                                        \
        bk[nf * 2 + kk] = *(const short8*)&Bp[((size_t)((wn * 4 + nf) * (KDIV32)            \
                                               + (t) * 2 + kk) * 64 + l) * 8];

#define COMPUTE1(bi, bk)                                                                    \
    _Pragma("unroll") for (int mg = 0; mg < 4; mg++) {                                      \
        short8 af[4];                                                                       \
        _Pragma("unroll") for (int mi = 0; mi < 2; mi++)                                    \
        _Pragma("unroll") for (int kk = 0; kk < 2; kk++)                                    \
            af[mi * 2 + kk] = *(const short8*)&ring[(bi) * 16384 +                          \
                (wm * 128 + (mg * 2 + mi) * 16 + llo) * 64 +                                \
                (((kk * 4 + lhi) ^ (llo & 7)) * 8)];                                        \
        __builtin_amdgcn_s_setprio(1);                                                      \
        _Pragma("unroll") for (int mi = 0; mi < 2; mi++)                                    \
        _Pragma("unroll") for (int nf = 0; nf < 4; nf++)                                    \
        _Pragma("unroll") for (int kk = 0; kk < 2; kk++)                                    \
            acc[mg * 2 + mi][nf] = __builtin_amdgcn_mfma_f32_16x16x32_bf16(                 \
                bk[nf * 2 + kk], af[mi * 2 + kk], acc[mg * 2 + mi][nf], 0, 0, 0);           \
        __builtin_amdgcn_s_setprio(0);                                                      \
    }

#define COMPUTE2(t2, bk)                                                                    \
    _Pragma("unroll") for (int mg = 0; mg < 4; mg++) {                                      \
        short8 af[4];                                                                       \
        _Pragma("unroll") for (int mi = 0; mi < 2; mi++)                                    \
        _Pragma("unroll") for (int kk = 0; kk < 2; kk++)                                    \
            af[mi * 2 + kk] = *(const short8*)&h1lds[                                       \
                (wm * 128 + (mg * 2 + mi) * 16 + llo) * 256 +                               \
                (((t2) * 8 | ((kk * 4 + lhi) ^ (llo & 7))) * 8)];                           \
        __builtin_amdgcn_s_setprio(1);                                                      \
        _Pragma("unroll") for (int mi = 0; mi < 2; mi++)                                    \
        _Pragma("unroll") for (int nf = 0; nf < 4; nf++)                                    \
        _Pragma("unroll") for (int kk = 0; kk < 2; kk++)                                    \
            acc[mg * 2 + mi][nf] = __builtin_amdgcn_mfma_f32_16x16x32_bf16(                 \
                bk[nf * 2 + kk], af[mi * 2 + kk], acc[mg * 2 + mi][nf], 0, 0, 0);           \
        __builtin_amdgcn_s_setprio(0);                                                      \
    }

#define TILE_BARRIER(n)                                                                     \
    __builtin_amdgcn_sched_barrier(0);                                                      \
    asm volatile("s_waitcnt vmcnt(" #n ")" ::: "memory");                                   \
    __builtin_amdgcn_s_barrier();                                                           \
    __builtin_amdgcn_sched_barrier(0);

__global__ __launch_bounds__(512, 2) void fused_mlp(
    const ushort* __restrict__ nf_bf, const int* __restrict__ idx,
    const ushort* __restrict__ pk1, const float* __restrict__ bc,
    const ushort* __restrict__ pk2, const float* __restrict__ b2,
    const float* __restrict__ W3, const float* __restrict__ b3,
    float* __restrict__ scores)
{
    __shared__ __align__(16) ushort smem[69632];   // 136 KB: ring 3x32K | h1 128K (alias), sc at +128K
    ushort* ring = smem;
    ushort* h1lds = smem;
    float* sc = (float*)&smem[65536];              // [4][256][2] = 8 KB

    const int tid = threadIdx.x;
    const int w = tid >> 6, l = tid & 63;
    const int llo = l & 15, lhi = l >> 4;
    const int wm = w >> 2, wn = w & 3;
    const int work = ((blockIdx.x & 7) << 6) + (blockIdx.x >> 3);   // 512 blocks, XCD-chunked
    const int m0 = work * 256;

    // staging: thread covers rows srow + 64*i (i=0..3), swizzled col chunk
    const int srow = tid >> 3;
    const int swz = 8 * ((l & 7) ^ (srow & 7));
    const ushort* rp0[4]; const ushort* rp1[4];
#pragma unroll
    for (int i = 0; i < 4; i++) {
        int2 ip = *(const int2*)&idx[2 * (m0 + i * 64 + srow)];
        rp0[i] = nf_bf + (size_t)ip.x * 256 + swz;
        rp1[i] = nf_bf + (size_t)ip.y * 256 + swz;
    }

    f32x4 acc[8][4];
#pragma unroll
    for (int a = 0; a < 8; a++)
#pragma unroll
        for (int nf = 0; nf < 4; nf++) acc[a][nf] = {0.f, 0.f, 0.f, 0.f};

    short8 bkA[8], bkB[8];

    auto stageA = [&](int bi, int t) {
#pragma unroll
        for (int i = 0; i < 4; i++) {
            const ushort* src = ((t < 4) ? rp0[i] : rp1[i]) + ((t & 3) << 6);
            gload_lds16(src, &ring[bi * 16384 + i * 4096 + w * 512]);
        }
    };

    // ---- prologue: stage tiles 0,1 ----
    stageA(0, 0);            // 4
    LOADB(bkA, pk1, 16, 0)   // +8 = 12
    stageA(1, 1);            // +4 = 16
    TILE_BARRIER(12)         // stage(0) retired

    // ---- phase 1: 8 K-tiles, 3-deep ring ----
#pragma unroll
    for (int t = 0; t < 8; t++) {
        if (t + 1 < 8) {
            if (t & 1) { LOADB(bkA, pk1, 16, t + 1) } else { LOADB(bkB, pk1, 16, t + 1) }
        }
        if (t + 2 < 8) stageA((t + 2) % 3, t + 2);
        if (t & 1) COMPUTE1(t % 3, bkB)
        else       COMPUTE1(t % 3, bkA)
        if (t < 6)      { TILE_BARRIER(12) }
        else if (t == 6){ TILE_BARRIER(8) }
    }

    // prefetch phase-2 B tile 0; syncthreads drains everything and closes ring reads
    LOADB(bkA, pk2, 8, 0)
    __syncthreads();

    // ---- epilogue 1: h1 = relu(acc + bc) -> LDS (bf16, XOR-swizzled chunks) ----
#pragma unroll
    for (int nf = 0; nf < 4; nf++) {
        int colb = wn * 64 + nf * 16 + lhi * 4;
        float4 bv = *(const float4*)&bc[colb];
        int c = colb >> 3;
        int coff = colb & 7;
#pragma unroll
        for (int mf = 0; mf < 8; mf++) {
            int row = wm * 128 + mf * 16 + llo;
            float v0 = fmaxf(acc[mf][nf][0] + bv.x, 0.f);
            float v1 = fmaxf(acc[mf][nf][1] + bv.y, 0.f);
            float v2 = fmaxf(acc[mf][nf][2] + bv.z, 0.f);
            float v3 = fmaxf(acc[mf][nf][3] + bv.w, 0.f);
            ushort4 o;
            o.x = f2bf(v0); o.y = f2bf(v1); o.z = f2bf(v2); o.w = f2bf(v3);
            int cs = (c & 24) | ((c & 7) ^ (row & 7));
            *(ushort4*)&h1lds[row * 256 + cs * 8 + coff] = o;
        }
    }
    __syncthreads();   // h1 visible

#pragma unroll
    for (int a = 0; a < 8; a++)
#pragma unroll
        for (int nf = 0; nf < 4; nf++) acc[a][nf] = {0.f, 0.f, 0.f, 0.f};

    // ---- phase 2: 4 K-tiles from LDS, barrier-free ----
#pragma unroll
    for (int t2 = 0; t2 < 4; t2++) {
        if (t2 + 1 < 4) {
            if (t2 & 1) { LOADB(bkA, pk2, 8, t2 + 1) } else { LOADB(bkB, pk2, 8, t2 + 1) }
        }
        if (t2 & 1) COMPUTE2(t2, bkB)
        else        COMPUTE2(t2, bkA)
    }

    // ---- epilogue 2: scores = relu(acc + b2) @ W3 + b3 ----
    float p0[8], p1[8];
#pragma unroll
    for (int a = 0; a < 8; a++) { p0[a] = 0.f; p1[a] = 0.f; }
#pragma unroll
    for (int nf = 0; nf < 4; nf++) {
        int colb = wn * 64 + nf * 16 + lhi * 4;
        float4 b2v = *(const float4*)&b2[colb];
        float2 w3a = ((const float2*)W3)[colb + 0];
        float2 w3b = ((const float2*)W3)[colb + 1];
        float2 w3c = ((const float2*)W3)[colb + 2];
        float2 w3d = ((const float2*)W3)[colb + 3];
#pragma unroll
        for (int a = 0; a < 8; a++) {
            float v0 = fmaxf(acc[a][nf][0] + b2v.x, 0.f);
            float v1 = fmaxf(acc[a][nf][1] + b2v.y, 0.f);
            float v2 = fmaxf(acc[a][nf][2] + b2v.z, 0.f);
            float v3 = fmaxf(acc[a][nf][3] + b2v.w, 0.f);
            p0[a] += v0 * w3a.x + v1 * w3b.x + v2 * w3c.x + v3 * w3d.x;
            p1[a] += v0 * w3a.y + v1 * w3b.y + v2 * w3c.y + v3 * w3d.y;
        }
    }
#pragma unroll
    for (int a = 0; a < 8; a++) {
        p0[a] += __shfl_xor(p0[a], 16); p0[a] += __shfl_xor(p0[a], 32);
        p1[a] += __shfl_xor(p1[a], 16); p1[a] += __shfl_xor(p1[a], 32);
    }
    if (l < 16) {
#pragma unroll
        for (int a = 0; a < 8; a++) {
            int r = wm * 128 + a * 16 + l;
            sc[(wn * 256 + r) * 2 + 0] = p0[a];
            sc[(wn * 256 + r) * 2 + 1] = p1[a];
        }
    }
    __syncthreads();
    {
        int row = tid >> 1, j = tid & 1;
        float s = b3[j];
#pragma unroll
        for (int q = 0; q < 4; q++) s += sc[(q * 256 + row) * 2 + j];
        scores[(size_t)(m0 + row) * 2 + j] = s;
    }
}

// ---------------- launch ----------------

extern "C" void kernel_launch(void* const* d_in, const int* in_sizes, int n_in,
                              void* d_out, int out_size, void* d_ws, size_t ws_size,
                              hipStream_t stream) {
    const float* node_feat = (const float*)d_in[0];
    const int* edge_candidate = (const int*)d_in[1];
    const int* nnodes = (const int*)d_in[2];
    const int* ncand = (const int*)d_in[3];
    const float* W_enc = (const float*)d_in[4];
    const float* b_enc = (const float*)d_in[5];
    const float* W1 = (const float*)d_in[6];
    const float* b1 = (const float*)d_in[7];
    const float* W2 = (const float*)d_in[8];
    const float* b2 = (const float*)d_in[9];
    const float* W3 = (const float*)d_in[10];
    const float* b3 = (const float*)d_in[11];

    const int D = 256;
    const int G = in_sizes[2];            // 64
    const int TOTN = in_sizes[0] / D;     // 32768
    const int E = in_sizes[1] / 2;        // 131072
    const int ENS = in_sizes[11];         // 2

    char* wsb = (char*)d_ws;
    size_t off = 0;
    auto alloc = [&](size_t bytes) -> void* {
        void* p = wsb + off;
        off += (bytes + 255) & ~(size_t)255;
        return p;
    };
    ushort* nf_bf = (ushort*)alloc((size_t)TOTN * D * 2);
    ushort* pk1   = (ushort*)alloc((size_t)512 * 256 * 2);
    ushort* pk2   = (ushort*)alloc((size_t)256 * 256 * 2);
    float*  bc    = (float*)alloc(256 * 4);
    int* idxb     = (int*)alloc((size_t)E * 2 * 4);

    float* scores_out = (float*)d_out;
    float* idx_out = scores_out + (size_t)E * ENS;

    // merged prep: conv | index | pack W2 | wc->pk1 + bc
    prep_k<<<3329, 256, 0, stream>>>(
        node_feat, nf_bf, TOTN * D / 4,
        edge_candidate, nnodes, ncand, G, E, idxb, idx_out,
        W2, pk2,
        W_enc, b_enc, W1, b1, pk1, bc);

    // fused L1+L2+L3
    fused_mlp<<<E / 256, 512, 0, stream>>>(nf_bf, idxb, pk1, bc, pk2, b2, W3, b3, scores_out);
}